// Round 12
// baseline (648.662 us; speedup 1.0000x reference)
//
#include <hip/hip_runtime.h>
#include <hip/hip_bf16.h>
#include <cstdint>
#include <cstddef>

#define M_DIM 8192
#define K_DIM 4096
#define N_DIM 4096
#define EPS 1e-5f

typedef __bf16 bf16x8 __attribute__((ext_vector_type(8)));
typedef unsigned short u16x8 __attribute__((ext_vector_type(8)));
typedef float f32x4 __attribute__((ext_vector_type(4)));

// ---------- helpers ----------

__device__ __forceinline__ unsigned short f2bf(float f) {
  unsigned int u = __builtin_bit_cast(unsigned int, f);
  u += 0x7fffu + ((u >> 16) & 1u);   // round-to-nearest-even
  return (unsigned short)(u >> 16);
}

// GELU(tanh-approx)+ReLU via identity 0.5y(1+tanh(w)) = y*sigmoid(2w):
// ge = y / (1 + exp2(-c2*z)), z = y + 0.044715 y^3, c2 = 2*0.7978845608*log2(e)
__device__ __forceinline__ float fused_epilogue(float acc, float inv, float shift) {
  float y = fmaf(acc, inv, shift);
  float y2 = y * y;
  float z = fmaf(0.044715f * y2, y, y);
  float e = __builtin_amdgcn_exp2f(-2.3022081f * z);
  float ge = y * __builtin_amdgcn_rcpf(1.0f + e);
  return fmaxf(ge, 0.0f);
}

__device__ __forceinline__ void gload_lds16(const void* gsrc, void* ldst) {
  __builtin_amdgcn_global_load_lds(
      (const __attribute__((address_space(1))) void*)gsrc,
      (__attribute__((address_space(3))) void*)ldst,
      16, 0, 0);
}

// ---------- pre-pass: fp32 -> bf16 conversions ----------

__global__ __launch_bounds__(256) void cvt_x_kernel(const float* __restrict__ x,
                                                    unsigned short* __restrict__ xb) {
  size_t i = ((size_t)blockIdx.x * 256 + threadIdx.x) * 8;
  float4 a = *reinterpret_cast<const float4*>(x + i);
  float4 b = *reinterpret_cast<const float4*>(x + i + 4);
  u16x8 o;
  o[0] = f2bf(a.x); o[1] = f2bf(a.y); o[2] = f2bf(a.z); o[3] = f2bf(a.w);
  o[4] = f2bf(b.x); o[5] = f2bf(b.y); o[6] = f2bf(b.z); o[7] = f2bf(b.w);
  *reinterpret_cast<u16x8*>(xb + i) = o;
}

// W [K][N] fp32 -> Wt [N][K] bf16 (transpose + convert)
__global__ __launch_bounds__(256) void cvt_w_transpose(const float* __restrict__ W,
                                                       unsigned short* __restrict__ Wt) {
  __shared__ float tile[32][33];
  const int tx = threadIdx.x & 31;
  const int tg = threadIdx.x >> 5;
  const int n0 = blockIdx.x * 32;
  const int k0 = blockIdx.y * 32;
#pragma unroll
  for (int j = 0; j < 4; ++j) {
    int k = tg * 4 + j;
    tile[k][tx] = W[(size_t)(k0 + k) * N_DIM + n0 + tx];
  }
  __syncthreads();
#pragma unroll
  for (int j = 0; j < 4; ++j) {
    int n = tg * 4 + j;
    Wt[(size_t)(n0 + n) * K_DIM + k0 + tx] = f2bf(tile[tx][n]);
  }
}

// ---------- main GEMM: 256x256, BK=32, 8 waves, ring-4 / stage-ahead-3 ----------
// LDS: 4 slots/operand x 8192 u16 (A @0, B @32768) = 128 KiB.
// Per K-tile tau:
//   top:    stage tile tau+3 -> slot (tau+3)%4       [4 gload_lds x 16B]
//   mid:    12 ds_reads for tile tau+1 from slot (tau+1)%4
//           [stage(tau+1) retired by vmcnt(4) at end of tau-1 -> data confirmed]
//   then:   32 MFMA on frags read during tau-1 (lgkm satisfied long ago)
//   end:    vmcnt(4)  [outstanding stage(tau+2)+stage(tau+3)=8 -> retires
//           stage(tau+2), exactly what reads during tau+1 need; stage(tau+3)
//           stays in flight ACROSS the barrier]; bare s_barrier.
// Slot-overwrite safety: stage(tau+3) at top of tau writes slot (tau-1)%4;
// that slot's ds_reads (issued during tau-2) completed before each wave's
// MFMA(tau-1) (compiler lgkm wait), which precede barrier(tau-1); the stage is
// issued after that barrier. First vmcnt(0) only at tile 125 (tail).
// sched_barrier(0) fences pin {stage}->{reads}->{MFMA} program order so the
// compiler cannot sink the prefetch reads to their consumers (R11 failure).
// Swizzle (bank-math, 0-conflict proven in R11): c8' = c8 ^ ((row>>1)&3).

#define STGA(j, S, TT)                                                             \
  gload_lds16(aP + (size_t)(j) * 128 * K_DIM + (size_t)(TT) * 32,                  \
              &lds[(S) * 8192 + (j) * 4096 + tid8])
#define STGB(j, S, TT)                                                             \
  gload_lds16(bP + (size_t)(j) * 128 * K_DIM + (size_t)(TT) * 32,                  \
              &lds[32768 + (S) * 8192 + (j) * 4096 + tid8])

#define LDS_FRAG(off) __builtin_bit_cast(bf16x8, *(const u16x8*)&lds[(off)])

// VM: 4 -> vmcnt(4); 0 -> vmcnt(0); -1 -> none. BAR: 1 -> s_barrier.
#define KT(T, SW, SR, AC, BC, AR, BR, STG, RD, VM, BAR) do {                       \
  if (STG) { STGA(0, SW, (T) + 3); STGA(1, SW, (T) + 3);                           \
             STGB(0, SW, (T) + 3); STGB(1, SW, (T) + 3); }                         \
  __builtin_amdgcn_sched_barrier(0);                                               \
  if (RD) {                                                                        \
    _Pragma("unroll") for (int ni = 0; ni < 4; ++ni)                               \
      BR[ni] = LDS_FRAG(32768 + (SR) * 8192 + bBase + ni * 512);                   \
    _Pragma("unroll") for (int mi = 0; mi < 8; ++mi)                               \
      AR[mi] = LDS_FRAG((SR) * 8192 + aBase + mi * 512);                           \
  }                                                                                \
  __builtin_amdgcn_sched_barrier(0);                                               \
  __builtin_amdgcn_s_setprio(1);                                                   \
  _Pragma("unroll") for (int mi = 0; mi < 8; ++mi)                                 \
  _Pragma("unroll") for (int ni = 0; ni < 4; ++ni)                                 \
    acc[mi][ni] = __builtin_amdgcn_mfma_f32_16x16x32_bf16(AC[mi], BC[ni],          \
                                                          acc[mi][ni], 0, 0, 0);   \
  __builtin_amdgcn_s_setprio(0);                                                   \
  if ((VM) == 4)      asm volatile("s_waitcnt vmcnt(4)" ::: "memory");             \
  else if ((VM) == 0) asm volatile("s_waitcnt vmcnt(0)" ::: "memory");             \
  if (BAR) __builtin_amdgcn_s_barrier();                                           \
} while (0)

__global__ __launch_bounds__(512, 2) void gemm_bf16_fused(
    const unsigned short* __restrict__ A,
    const unsigned short* __restrict__ Bt,
    const float* __restrict__ gam, const float* __restrict__ bet,
    const float* __restrict__ mu, const float* __restrict__ var,
    float* __restrict__ C) {
  __shared__ __align__(16) unsigned short lds[65536];  // 128 KiB

  const int tid = threadIdx.x;
  const int wave = tid >> 6;
  const int lane = tid & 63;
  const int l15 = lane & 15, l4 = lane >> 4;
  const int wr = wave >> 2, wc = wave & 3;   // 2x4 wave grid; per-wave out 128x64
  const int tid8 = tid * 8;                  // linear gload_lds dest (elem units)

  // XCD-aware swizzle: 512 blocks, 512 % 8 == 0 -> bijective
  const int bid = (int)blockIdx.x;
  const int swz = (bid & 7) * 64 + (bid >> 3);
  const int bx = swz & 15;                   // 16 N-tiles
  const int by = swz >> 4;                   // 32 M-tiles
  const size_t bm = (size_t)by * 256;
  const size_t bn = (size_t)bx * 256;

  // stage source (pre-swizzled global per thread): row (within 128-half) = tid>>2,
  // col8_src = (tid&3) ^ ((row>>1)&3) = (tid&3) ^ ((tid>>3)&3)
  const int srow = tid >> 2;
  const int scol = (tid & 3) ^ ((tid >> 3) & 3);
  const unsigned short* aP = A  + (bm + (size_t)srow) * K_DIM + scol * 8;
  const unsigned short* bP = Bt + (bn + (size_t)srow) * K_DIM + scol * 8;

  // ds_read bases (elem units); xk = (l4 ^ ((row>>1)&3))*8, (row>>1)&3 == (l15>>1)&3
  const int xk = (l4 ^ ((l15 >> 1) & 3)) * 8;
  const int aBase = (wr * 128 + l15) * 32 + xk;   // + mi*512
  const int bBase = (wc * 64 + l15) * 32 + xk;    // + ni*512 (within B slot)

  f32x4 acc[8][4] = {};
  bf16x8 a0[8], b0[4], a1[8], b1[4];

  // ---- prologue: stage tiles 0,1,2 -> slots 0,1,2; vmcnt(4) confirms 0 AND 1 ----
  STGA(0, 0, 0); STGA(1, 0, 0); STGB(0, 0, 0); STGB(1, 0, 0);
  asm volatile("" ::: "memory");
  STGA(0, 1, 1); STGA(1, 1, 1); STGB(0, 1, 1); STGB(1, 1, 1);
  asm volatile("" ::: "memory");
  STGA(0, 2, 2); STGA(1, 2, 2); STGB(0, 2, 2); STGB(1, 2, 2);
  asm volatile("s_waitcnt vmcnt(4)" ::: "memory");   // tiles 0,1 landed; 2 in flight
  __builtin_amdgcn_s_barrier();
#pragma unroll
  for (int ni = 0; ni < 4; ++ni) b0[ni] = LDS_FRAG(32768 + bBase + ni * 512);
#pragma unroll
  for (int mi = 0; mi < 8; ++mi) a0[mi] = LDS_FRAG(aBase + mi * 512);

  // ---- main loop: tiles 0..119, unroll 4 (= ring period; frag parity = T&1) ----
  for (int t = 0; t < 120; t += 4) {
    KT(t + 0, 3, 1, a0, b0, a1, b1, 1, 1, 4, 1);
    KT(t + 1, 0, 2, a1, b1, a0, b0, 1, 1, 4, 1);
    KT(t + 2, 1, 3, a0, b0, a1, b1, 1, 1, 4, 1);
    KT(t + 3, 2, 0, a1, b1, a0, b0, 1, 1, 4, 1);
  }
  // ---- tail: tiles 120..127 (last stage: tile 127 at top of 124) ----
  KT(120, 3, 1, a0, b0, a1, b1, 1, 1, 4, 1);
  KT(121, 0, 2, a1, b1, a0, b0, 1, 1, 4, 1);
  KT(122, 1, 3, a0, b0, a1, b1, 1, 1, 4, 1);
  KT(123, 2, 0, a1, b1, a0, b0, 1, 1, 4, 1);
  KT(124, 3, 1, a0, b0, a1, b1, 1, 1, 4, 1);   // stages 127 -> slot 3; retires stage(126)
  KT(125, 0, 2, a1, b1, a0, b0, 0, 1, 0, 1);   // vmcnt(0): stage(127) confirmed
  KT(126, 0, 3, a0, b0, a1, b1, 0, 1, -1, 1);  // reads tile 127 (slot 3)
  KT(127, 0, 0, a1, b1, a0, b0, 0, 0, -1, 0);  // MFMA only

  // ---- epilogue: fused BN + GELU + ReLU ----
  const int row0 = (int)bm + wr * 128;
  const int col0 = (int)bn + wc * 64;
#pragma unroll
  for (int ni = 0; ni < 4; ++ni) {
    const int col = col0 + ni * 16 + l15;
    const float inv = rsqrtf(var[col] + EPS) * gam[col];
    const float shift = fmaf(-mu[col], inv, bet[col]);
#pragma unroll
    for (int mi = 0; mi < 8; ++mi) {
      const int r0 = row0 + mi * 16 + l4 * 4;
#pragma unroll
      for (int r = 0; r < 4; ++r)
        C[(size_t)(r0 + r) * N_DIM + col] = fused_epilogue(acc[mi][ni][r], inv, shift);
    }
  }
}

// ---------- fallback (only if ws too small): fp32 tiled GEMM ----------

__global__ __launch_bounds__(256) void gemm_f32_fallback(
    const float* __restrict__ A, const float* __restrict__ W,
    const float* __restrict__ gam, const float* __restrict__ bet,
    const float* __restrict__ mu, const float* __restrict__ var,
    float* __restrict__ C) {
  __shared__ float As[16][65];
  __shared__ float Bs[16][65];
  const int tid = threadIdx.x;
  const int tx = tid & 15, ty = tid >> 4;
  const int bn0 = blockIdx.x * 64, bm0 = blockIdx.y * 64;
  float acc[4][4] = {};
  for (int k0 = 0; k0 < K_DIM; k0 += 16) {
#pragma unroll
    for (int j = 0; j < 4; ++j)
      As[tid & 15][(tid >> 4) * 4 + j] =
          A[(size_t)(bm0 + (tid >> 4) * 4 + j) * K_DIM + k0 + (tid & 15)];
#pragma unroll
    for (int j = 0; j < 4; ++j)
      Bs[tid >> 4][(tid & 15) * 4 + j] =
          W[(size_t)(k0 + (tid >> 4)) * N_DIM + bn0 + (tid & 15) * 4 + j];
    __syncthreads();
#pragma unroll
    for (int kk = 0; kk < 16; ++kk) {
      float a_[4], b_[4];
#pragma unroll
      for (int i = 0; i < 4; ++i) a_[i] = As[kk][ty * 4 + i];
#pragma unroll
      for (int j = 0; j < 4; ++j) b_[j] = Bs[kk][tx * 4 + j];
#pragma unroll
      for (int i = 0; i < 4; ++i)
#pragma unroll
        for (int j = 0; j < 4; ++j)
          acc[i][j] = fmaf(a_[i], b_[j], acc[i][j]);
    }
    __syncthreads();
  }
#pragma unroll
  for (int j = 0; j < 4; ++j) {
    const int col = bn0 + tx * 4 + j;
    const float inv = rsqrtf(var[col] + EPS) * gam[col];
    const float shift = fmaf(-mu[col], inv, bet[col]);
#pragma unroll
    for (int i = 0; i < 4; ++i) {
      float y = fmaf(acc[i][j], inv, shift);
      float y2 = y * y;
      float z = fmaf(0.044715f * y2, y, y);
      float e = __builtin_amdgcn_exp2f(-2.3022081f * z);
      float ge = y * __builtin_amdgcn_rcpf(1.0f + e);
      C[(size_t)(bm0 + ty * 4 + i) * N_DIM + col] = fmaxf(ge, 0.0f);
    }
  }
}

// ---------- launch ----------

extern "C" void kernel_launch(void* const* d_in, const int* in_sizes, int n_in,
                              void* d_out, int out_size, void* d_ws, size_t ws_size,
                              hipStream_t stream) {
  const float* x  = (const float*)d_in[0];
  const float* w  = (const float*)d_in[1];
  const float* gg = (const float*)d_in[2];
  const float* bb = (const float*)d_in[3];
  const float* mu = (const float*)d_in[4];
  const float* vr = (const float*)d_in[5];
  float* out = (float*)d_out;

  const size_t xb_bytes = (size_t)M_DIM * K_DIM * 2;
  const size_t wt_bytes = (size_t)K_DIM * N_DIM * 2;

  if (ws_size >= xb_bytes + wt_bytes) {
    unsigned short* xb = (unsigned short*)d_ws;
    unsigned short* wt = xb + (size_t)M_DIM * K_DIM;
    cvt_x_kernel<<<dim3((M_DIM * (size_t)K_DIM) / 8 / 256), dim3(256), 0, stream>>>(x, xb);
    cvt_w_transpose<<<dim3(N_DIM / 32, K_DIM / 32), dim3(256), 0, stream>>>(w, wt);
    gemm_bf16_fused<<<dim3((M_DIM / 256) * (N_DIM / 256)), dim3(512), 0, stream>>>(
        xb, wt, gg, bb, mu, vr, out);
  } else {
    gemm_f32_fallback<<<dim3(N_DIM / 64, M_DIM / 64), dim3(256), 0, stream>>>(
        x, w, gg, bb, mu, vr, out);
  }
}

// Round 13
// 353.442 us; speedup vs baseline: 1.8353x; 1.8353x over previous
//
#include <hip/hip_runtime.h>
#include <hip/hip_bf16.h>
#include <cstdint>
#include <cstddef>

#define M_DIM 8192
#define K_DIM 4096
#define N_DIM 4096
#define EPS 1e-5f

typedef __bf16 bf16x8 __attribute__((ext_vector_type(8)));
typedef unsigned short u16x8 __attribute__((ext_vector_type(8)));
typedef unsigned int u32x4 __attribute__((ext_vector_type(4)));
typedef float f32x4 __attribute__((ext_vector_type(4)));

// ---------- helpers ----------

__device__ __forceinline__ unsigned short f2bf(float f) {
  unsigned int u = __builtin_bit_cast(unsigned int, f);
  u += 0x7fffu + ((u >> 16) & 1u);   // round-to-nearest-even
  return (unsigned short)(u >> 16);
}

// GELU(tanh-approx)+ReLU via identity 0.5y(1+tanh(w)) = y*sigmoid(2w):
// ge = y / (1 + exp2(-c2*z)), z = y + 0.044715 y^3, c2 = 2*0.7978845608*log2(e)
__device__ __forceinline__ float fused_epilogue(float acc, float inv, float shift) {
  float y = fmaf(acc, inv, shift);
  float y2 = y * y;
  float z = fmaf(0.044715f * y2, y, y);
  float e = __builtin_amdgcn_exp2f(-2.3022081f * z);
  float ge = y * __builtin_amdgcn_rcpf(1.0f + e);
  return fmaxf(ge, 0.0f);
}

__device__ __forceinline__ void gload_lds16(const void* gsrc, void* ldst) {
  __builtin_amdgcn_global_load_lds(
      (const __attribute__((address_space(1))) void*)gsrc,
      (__attribute__((address_space(3))) void*)ldst,
      16, 0, 0);
}

// v_cvt_pk_bf16_f32: packs bf16(lo),bf16(hi) into one dword (RNE)
#define CVT_PK(d, lo, hi) \
  asm("v_cvt_pk_bf16_f32 %0, %1, %2" : "=v"(d) : "v"(lo), "v"(hi))

// ---------- pre-pass: W [K][N] fp32 -> Wt [N][K] bf16 (transpose + convert) ----------

__global__ __launch_bounds__(256) void cvt_w_transpose(const float* __restrict__ W,
                                                       unsigned short* __restrict__ Wt) {
  __shared__ float tile[32][33];
  const int tx = threadIdx.x & 31;
  const int tg = threadIdx.x >> 5;
  const int n0 = blockIdx.x * 32;
  const int k0 = blockIdx.y * 32;
#pragma unroll
  for (int j = 0; j < 4; ++j) {
    int k = tg * 4 + j;
    tile[k][tx] = W[(size_t)(k0 + k) * N_DIM + n0 + tx];
  }
  __syncthreads();
#pragma unroll
  for (int j = 0; j < 4; ++j) {
    int n = tg * 4 + j;
    Wt[(size_t)(n0 + n) * K_DIM + k0 + tx] = f2bf(tile[tx][n]);
  }
}

// ---------- main GEMM: 256x256, BK=64, 8 waves, fused-A-convert, 1 barrier/tile ----
// A: raw fp32 [M][K] (no pre-pass). Per tile: 8x float4 loads (A(t+1), pre-swizzled
// per-lane k-offset) at tile top; mid vmcnt(0) retires B(t+1)+A-glb(t+1);
// 16x v_cvt_pk_bf16_f32 + 4x ds_write_b128 reproduce EXACTLY the LDS image the
// R4 gload_lds path wrote (read side byte-identical, 0-conflict proven).
// B: gload_lds + parity double-buffer as R4, but staged AFTER the tile-end
// barrier (all waves' b1 reads drained by lgkm(0) before barrier -> race-free).
// Ledger/tile: top out = B(t+1)x4 + Aglb(t+1)x8; mid vmcnt(0) drains both
// (B slack ~1.5 tiles, A slack ~600-900cyc L3); end lgkm(0)+barrier; then
// STG_B(t+2) issues (slack ~1.5 tiles to its vmcnt). ONE barrier per tile.

#define STG_B(h, j, PAR, T)                                                        \
  gload_lds16(bS + (size_t)((h)*128 + 64*(j)) * K_DIM + (size_t)((T) + 2) * 64,    \
              &lds[32768 + (2*(PAR) + (h)) * 8192 + (wave + 8*(j)) * 512])

#define LDS_FRAG(off) __builtin_bit_cast(bf16x8, *(const u16x8*)&lds[(off)])

// A(t+1) ds_write dest (u16 units): written during tile t (parity PAR)
#define ADST(h, j, PAR) ((2*(1-(PAR)) + (h)) * 8192 + (wave + 8*(j)) * 512 + lane * 8)

#define CVT_STORE(fa, fb, dst) do {                                                \
  u32x4 wv_;                                                                       \
  CVT_PK(wv_[0], (fa).x, (fa).y); CVT_PK(wv_[1], (fa).z, (fa).w);                  \
  CVT_PK(wv_[2], (fb).x, (fb).y); CVT_PK(wv_[3], (fb).z, (fb).w);                  \
  *(u32x4*)&lds[(dst)] = wv_;                                                      \
} while (0)

#define KTILE(T, PAR, LDA, STB, LAST) do {                                         \
  const int sa = (PAR) * 16384 + saW;                                              \
  const int sb = (PAR) * 16384 + sbW;                                              \
  float4 f00a, f00b, f01a, f01b, f10a, f10b, f11a, f11b;                           \
  if (LDA) {                                                                       \
    const float* ab = aF + (size_t)((T) + 1) * 64;                                 \
    f00a = *(const float4*)(ab);                                                   \
    f00b = *(const float4*)(ab + 4);                                               \
    f01a = *(const float4*)(ab + (size_t)64 * K_DIM);                              \
    f01b = *(const float4*)(ab + (size_t)64 * K_DIM + 4);                          \
    f10a = *(const float4*)(ab + (size_t)128 * K_DIM);                             \
    f10b = *(const float4*)(ab + (size_t)128 * K_DIM + 4);                         \
    f11a = *(const float4*)(ab + (size_t)192 * K_DIM);                             \
    f11b = *(const float4*)(ab + (size_t)192 * K_DIM + 4);                         \
  }                                                                                \
  __builtin_amdgcn_sched_barrier(0);     /* pin A-load issue at tile top */        \
  bf16x8 b0[4], ak0[8];                                                            \
  _Pragma("unroll") for (int ni = 0; ni < 4; ++ni)                                 \
    b0[ni] = LDS_FRAG(sb + bro + ni * 1024 + xk0);                                 \
  _Pragma("unroll") for (int mi = 0; mi < 8; ++mi)                                 \
    ak0[mi] = LDS_FRAG(sa + aro + mi * 1024 + xk0);                                \
  __builtin_amdgcn_s_setprio(1);                                                   \
  _Pragma("unroll") for (int mi = 0; mi < 8; ++mi)                                 \
  _Pragma("unroll") for (int ni = 0; ni < 4; ++ni)                                 \
    acc[mi][ni] = __builtin_amdgcn_mfma_f32_16x16x32_bf16(ak0[mi], b0[ni],         \
                                                          acc[mi][ni], 0, 0, 0);   \
  __builtin_amdgcn_s_setprio(0);                                                   \
  if (LDA) {                                                                       \
    asm volatile("s_waitcnt vmcnt(0)" ::: "memory");  /* B(t+1)+Aglb(t+1) */       \
    CVT_STORE(f00a, f00b, ADST(0, 0, PAR));                                        \
    CVT_STORE(f01a, f01b, ADST(0, 1, PAR));                                        \
    CVT_STORE(f10a, f10b, ADST(1, 0, PAR));                                        \
    CVT_STORE(f11a, f11b, ADST(1, 1, PAR));                                        \
  }                                                                                \
  bf16x8 b1[4], ak1[8];                                                            \
  _Pragma("unroll") for (int ni = 0; ni < 4; ++ni)                                 \
    b1[ni] = LDS_FRAG(sb + bro + ni * 1024 + xk1);                                 \
  _Pragma("unroll") for (int mi = 0; mi < 8; ++mi)                                 \
    ak1[mi] = LDS_FRAG(sa + aro + mi * 1024 + xk1);                                \
  __builtin_amdgcn_s_setprio(1);                                                   \
  _Pragma("unroll") for (int mi = 0; mi < 8; ++mi)                                 \
  _Pragma("unroll") for (int ni = 0; ni < 4; ++ni)                                 \
    acc[mi][ni] = __builtin_amdgcn_mfma_f32_16x16x32_bf16(ak1[mi], b1[ni],         \
                                                          acc[mi][ni], 0, 0, 0);   \
  __builtin_amdgcn_s_setprio(0);                                                   \
  if (!(LAST)) {                                                                   \
    asm volatile("s_waitcnt lgkmcnt(0)" ::: "memory");                             \
    __builtin_amdgcn_s_barrier();                                                  \
    if (STB) { STG_B(0, 0, PAR, T); STG_B(0, 1, PAR, T);                           \
               STG_B(1, 0, PAR, T); STG_B(1, 1, PAR, T); }                         \
    asm volatile("" ::: "memory");                                                 \
  }                                                                                \
} while (0)

__global__ __launch_bounds__(512, 2) void gemm_bf16_fused(
    const float* __restrict__ A32,
    const unsigned short* __restrict__ Bt,
    const float* __restrict__ gam, const float* __restrict__ bet,
    const float* __restrict__ mu, const float* __restrict__ var,
    float* __restrict__ C) {
  __shared__ __align__(16) unsigned short lds[65536];  // 128 KiB

  const int tid = threadIdx.x;
  const int wave = tid >> 6;
  const int lane = tid & 63;
  const int l15 = lane & 15, l4 = lane >> 4;
  const int wr = wave >> 2, wc = wave & 3;   // 2x4 wave grid; per-wave out 128x64

  // XCD-aware swizzle: 512 blocks, 512 % 8 == 0 -> bijective
  const int bid = (int)blockIdx.x;
  const int swz = (bid & 7) * 64 + (bid >> 3);
  const int bx = swz & 15;                   // 16 N-tiles
  const int by = swz >> 4;                   // 32 M-tiles
  const size_t bm = (size_t)by * 256;
  const size_t bn = (size_t)bx * 256;

  // staging lane geometry (pre-swizzled source k-chunk; linear LDS dest)
  const int lr = lane >> 3, lc = lane & 7;
  // A fp32 source base: rows wave*8+lr (+{0,64,128,192} per (h,j)), k-chunk (lc^lr)*8
  const float* aF = A32 + (bm + (size_t)(wave * 8 + lr)) * K_DIM + (lc ^ lr) * 8;
  // B bf16 source (R4-proven)
  const unsigned short* bS = Bt + (bn + (size_t)(wave * 8 + lr)) * K_DIM + (lc ^ lr) * 8;

  // ds_read fragment offsets (u16 units); col8' = col8 ^ (row&7), row&7 == l15&7
  const int xk0 = ((l4)     ^ (l15 & 7)) * 8;
  const int xk1 = ((l4 | 4) ^ (l15 & 7)) * 8;
  const int aro = l15 * 64;
  const int bro = (wc & 1) * 4096 + l15 * 64;
  const int saW = wr * 8192;
  const int sbW = 32768 + (wc >> 1) * 8192;

  f32x4 acc[8][4] = {};

  // ---- prologue ----
  // A(0) fp32 loads (oldest in vm queue)
  float4 p00a = *(const float4*)(aF);
  float4 p00b = *(const float4*)(aF + 4);
  float4 p01a = *(const float4*)(aF + (size_t)64 * K_DIM);
  float4 p01b = *(const float4*)(aF + (size_t)64 * K_DIM + 4);
  float4 p10a = *(const float4*)(aF + (size_t)128 * K_DIM);
  float4 p10b = *(const float4*)(aF + (size_t)128 * K_DIM + 4);
  float4 p11a = *(const float4*)(aF + (size_t)192 * K_DIM);
  float4 p11b = *(const float4*)(aF + (size_t)192 * K_DIM + 4);
  __builtin_amdgcn_sched_barrier(0);
  // B(0) -> parity-0 slots, B(1) -> parity-1 slots
  STG_B(0, 0, 0, -2); STG_B(0, 1, 0, -2); STG_B(1, 0, 0, -2); STG_B(1, 1, 0, -2);
  asm volatile("" ::: "memory");
  STG_B(0, 0, 1, -1); STG_B(0, 1, 1, -1); STG_B(1, 0, 1, -1); STG_B(1, 1, 1, -1);
  asm volatile("s_waitcnt vmcnt(8)" ::: "memory");   // A(0) fp32 landed
  // A(0) -> parity-0 A slots (PAR'=1 formula: slots h*8192)
  CVT_STORE(p00a, p00b, ADST(0, 0, 1));
  CVT_STORE(p01a, p01b, ADST(0, 1, 1));
  CVT_STORE(p10a, p10b, ADST(1, 0, 1));
  CVT_STORE(p11a, p11b, ADST(1, 1, 1));
  asm volatile("s_waitcnt vmcnt(4)" ::: "memory");   // B(0) landed; B(1) in flight
  asm volatile("s_waitcnt lgkmcnt(0)" ::: "memory");
  __builtin_amdgcn_s_barrier();

  // ---- main loop: 64 K-tiles ----
  for (int t = 0; t < 60; t += 2) {
    KTILE(t,     0, 1, 1, 0);
    KTILE(t + 1, 1, 1, 1, 0);
  }
  KTILE(60, 0, 1, 1, 0);
  KTILE(61, 1, 1, 1, 0);   // stages B(63); loads+writes A(62)
  KTILE(62, 0, 1, 0, 0);   // loads+writes A(63); no B stage
  KTILE(63, 1, 0, 0, 1);   // final: no loads, no vmcnt, no barrier

  // ---- epilogue: fused BN + GELU + ReLU ----
  const int row0 = (int)bm + wr * 128;
  const int col0 = (int)bn + wc * 64;
#pragma unroll
  for (int ni = 0; ni < 4; ++ni) {
    const int col = col0 + ni * 16 + l15;
    const float inv = rsqrtf(var[col] + EPS) * gam[col];
    const float shift = fmaf(-mu[col], inv, bet[col]);
#pragma unroll
    for (int mi = 0; mi < 8; ++mi) {
      const int r0 = row0 + mi * 16 + l4 * 4;
#pragma unroll
      for (int r = 0; r < 4; ++r)
        C[(size_t)(r0 + r) * N_DIM + col] = fused_epilogue(acc[mi][ni][r], inv, shift);
    }
  }
}

// ---------- fallback (only if ws too small): fp32 tiled GEMM ----------

__global__ __launch_bounds__(256) void gemm_f32_fallback(
    const float* __restrict__ A, const float* __restrict__ W,
    const float* __restrict__ gam, const float* __restrict__ bet,
    const float* __restrict__ mu, const float* __restrict__ var,
    float* __restrict__ C) {
  __shared__ float As[16][65];
  __shared__ float Bs[16][65];
  const int tid = threadIdx.x;
  const int tx = tid & 15, ty = tid >> 4;
  const int bn0 = blockIdx.x * 64, bm0 = blockIdx.y * 64;
  float acc[4][4] = {};
  for (int k0 = 0; k0 < K_DIM; k0 += 16) {
#pragma unroll
    for (int j = 0; j < 4; ++j)
      As[tid & 15][(tid >> 4) * 4 + j] =
          A[(size_t)(bm0 + (tid >> 4) * 4 + j) * K_DIM + k0 + (tid & 15)];
#pragma unroll
    for (int j = 0; j < 4; ++j)
      Bs[tid >> 4][(tid & 15) * 4 + j] =
          W[(size_t)(k0 + (tid >> 4)) * N_DIM + bn0 + (tid & 15) * 4 + j];
    __syncthreads();
#pragma unroll
    for (int kk = 0; kk < 16; ++kk) {
      float a_[4], b_[4];
#pragma unroll
      for (int i = 0; i < 4; ++i) a_[i] = As[kk][ty * 4 + i];
#pragma unroll
      for (int j = 0; j < 4; ++j) b_[j] = Bs[kk][tx * 4 + j];
#pragma unroll
      for (int i = 0; i < 4; ++i)
#pragma unroll
        for (int j = 0; j < 4; ++j)
          acc[i][j] = fmaf(a_[i], b_[j], acc[i][j]);
    }
    __syncthreads();
  }
#pragma unroll
  for (int j = 0; j < 4; ++j) {
    const int col = bn0 + tx * 4 + j;
    const float inv = rsqrtf(var[col] + EPS) * gam[col];
    const float shift = fmaf(-mu[col], inv, bet[col]);
#pragma unroll
    for (int i = 0; i < 4; ++i) {
      float y = fmaf(acc[i][j], inv, shift);
      float y2 = y * y;
      float z = fmaf(0.044715f * y2, y, y);
      float e = __builtin_amdgcn_exp2f(-2.3022081f * z);
      float ge = y * __builtin_amdgcn_rcpf(1.0f + e);
      C[(size_t)(bm0 + ty * 4 + i) * N_DIM + col] = fmaxf(ge, 0.0f);
    }
  }
}

// ---------- launch ----------

extern "C" void kernel_launch(void* const* d_in, const int* in_sizes, int n_in,
                              void* d_out, int out_size, void* d_ws, size_t ws_size,
                              hipStream_t stream) {
  const float* x  = (const float*)d_in[0];
  const float* w  = (const float*)d_in[1];
  const float* gg = (const float*)d_in[2];
  const float* bb = (const float*)d_in[3];
  const float* mu = (const float*)d_in[4];
  const float* vr = (const float*)d_in[5];
  float* out = (float*)d_out;

  const size_t wt_bytes = (size_t)K_DIM * N_DIM * 2;

  if (ws_size >= wt_bytes) {
    unsigned short* wt = (unsigned short*)d_ws;
    cvt_w_transpose<<<dim3(N_DIM / 32, K_DIM / 32), dim3(256), 0, stream>>>(w, wt);
    gemm_bf16_fused<<<dim3((M_DIM / 256) * (N_DIM / 256)), dim3(512), 0, stream>>>(
        x, wt, gg, bb, mu, vr, out);
  } else {
    gemm_f32_fallback<<<dim3(N_DIM / 64, M_DIM / 64), dim3(256), 0, stream>>>(
        x, w, gg, bb, mu, vr, out);
  }
}

// Round 14
// 329.377 us; speedup vs baseline: 1.9694x; 1.0731x over previous
//
#include <hip/hip_runtime.h>
#include <hip/hip_bf16.h>
#include <cstdint>
#include <cstddef>

#define M_DIM 8192
#define K_DIM 4096
#define N_DIM 4096
#define EPS 1e-5f

typedef __bf16 bf16x8 __attribute__((ext_vector_type(8)));
typedef unsigned short u16x8 __attribute__((ext_vector_type(8)));
typedef float f32x4 __attribute__((ext_vector_type(4)));

// ---------- helpers ----------

__device__ __forceinline__ unsigned short f2bf(float f) {
  unsigned int u = __builtin_bit_cast(unsigned int, f);
  u += 0x7fffu + ((u >> 16) & 1u);   // round-to-nearest-even
  return (unsigned short)(u >> 16);
}

// GELU(tanh-approx)+ReLU via identity 0.5y(1+tanh(w)) = y*sigmoid(2w):
// ge = y / (1 + exp2(-c2*z)), z = y + 0.044715 y^3, c2 = 2*0.7978845608*log2(e)
__device__ __forceinline__ float fused_epilogue(float acc, float inv, float shift) {
  float y = fmaf(acc, inv, shift);
  float y2 = y * y;
  float z = fmaf(0.044715f * y2, y, y);
  float e = __builtin_amdgcn_exp2f(-2.3022081f * z);
  float ge = y * __builtin_amdgcn_rcpf(1.0f + e);
  return fmaxf(ge, 0.0f);
}

__device__ __forceinline__ void gload_lds16(const void* gsrc, void* ldst) {
  __builtin_amdgcn_global_load_lds(
      (const __attribute__((address_space(1))) void*)gsrc,
      (__attribute__((address_space(3))) void*)ldst,
      16, 0, 0);
}

// ---------- pre-pass: fp32 -> bf16 conversions ----------

__global__ __launch_bounds__(256) void cvt_x_kernel(const float* __restrict__ x,
                                                    unsigned short* __restrict__ xb) {
  size_t i = ((size_t)blockIdx.x * 256 + threadIdx.x) * 8;
  float4 a = *reinterpret_cast<const float4*>(x + i);
  float4 b = *reinterpret_cast<const float4*>(x + i + 4);
  u16x8 o;
  o[0] = f2bf(a.x); o[1] = f2bf(a.y); o[2] = f2bf(a.z); o[3] = f2bf(a.w);
  o[4] = f2bf(b.x); o[5] = f2bf(b.y); o[6] = f2bf(b.z); o[7] = f2bf(b.w);
  *reinterpret_cast<u16x8*>(xb + i) = o;
}

// W [K][N] fp32 -> Wt [N][K] bf16 (transpose + convert)
__global__ __launch_bounds__(256) void cvt_w_transpose(const float* __restrict__ W,
                                                       unsigned short* __restrict__ Wt) {
  __shared__ float tile[32][33];
  const int tx = threadIdx.x & 31;
  const int tg = threadIdx.x >> 5;
  const int n0 = blockIdx.x * 32;
  const int k0 = blockIdx.y * 32;
#pragma unroll
  for (int j = 0; j < 4; ++j) {
    int k = tg * 4 + j;
    tile[k][tx] = W[(size_t)(k0 + k) * N_DIM + n0 + tx];
  }
  __syncthreads();
#pragma unroll
  for (int j = 0; j < 4; ++j) {
    int n = tg * 4 + j;
    Wt[(size_t)(n0 + n) * K_DIM + k0 + tx] = f2bf(tile[tx][n]);
  }
}

// ---------- main GEMM: 128x256 tile, BK=32, 8 waves, dbuf-2, 2 blocks/CU ----------
// Geometry chosen for the 128-reg/wave occupancy wall: per-wave 64x64 output
// (acc = 64 AGPR) + ~50 arch regs ≈ 114 total -> 4 waves/SIMD (2 blocks/CU).
// Cross-block co-scheduling (m114/m97 mechanism) hides the vmcnt(0) barrier
// drain that bounded all 1-block/CU schedules at ~4690 cyc/tile.
// LDS: dbuf-2: A 2x4096 u16 (128x32) @0, B 2x8192 u16 (256x32) @8192 = 48 KiB.
// Swizzle (R11/R12-measured 0-conflict): c8' = c8 ^ ((row>>1)&3); pre-swizzled
// global source, linear gload_lds dest, swizzled ds_read.
// Per tile t: stage(t+1)->slots (t+1)&1 (3 gloads/thread); read slot t&1
// (8 ds_read_b128); 16 MFMA; lgkm(0)+vmcnt(0)+barrier (m97 drain).

#define SLOTA(p) ((p) * 4096)
#define SLOTB(p) (8192 + (p) * 8192)

#define STG(T, P) do {                                                             \
  gload_lds16(aP + (size_t)(T) * 32,                    &lds[SLOTA(P) + wv512]);   \
  gload_lds16(bP + (size_t)(T) * 32,                    &lds[SLOTB(P) + wv512]);   \
  gload_lds16(bP + (size_t)128 * K_DIM + (size_t)(T) * 32,                         \
              &lds[SLOTB(P) + 4096 + wv512]);                                      \
} while (0)

#define LDS_FRAG(off) __builtin_bit_cast(bf16x8, *(const u16x8*)&lds[(off)])

#define KTILE(T, PAR, STG_, LAST) do {                                             \
  if (STG_) STG((T) + 1, 1 - (PAR));                                               \
  asm volatile("" ::: "memory");                                                   \
  bf16x8 aq[4], bq[4];                                                             \
  _Pragma("unroll") for (int ni = 0; ni < 4; ++ni)                                 \
    bq[ni] = LDS_FRAG(SLOTB(PAR) + bBase + ni * 512);                              \
  _Pragma("unroll") for (int mi = 0; mi < 4; ++mi)                                 \
    aq[mi] = LDS_FRAG(SLOTA(PAR) + aBase + mi * 512);                              \
  __builtin_amdgcn_s_setprio(1);                                                   \
  _Pragma("unroll") for (int mi = 0; mi < 4; ++mi)                                 \
  _Pragma("unroll") for (int ni = 0; ni < 4; ++ni)                                 \
    acc[mi][ni] = __builtin_amdgcn_mfma_f32_16x16x32_bf16(aq[mi], bq[ni],          \
                                                          acc[mi][ni], 0, 0, 0);   \
  __builtin_amdgcn_s_setprio(0);                                                   \
  if (!(LAST)) {                                                                   \
    asm volatile("s_waitcnt lgkmcnt(0)" ::: "memory");                             \
    asm volatile("s_waitcnt vmcnt(0)" ::: "memory");                               \
    __builtin_amdgcn_s_barrier();                                                  \
  }                                                                                \
} while (0)

__global__ __launch_bounds__(512, 4) void gemm_bf16_fused(
    const unsigned short* __restrict__ A,
    const unsigned short* __restrict__ Bt,
    const float* __restrict__ gam, const float* __restrict__ bet,
    const float* __restrict__ mu, const float* __restrict__ var,
    float* __restrict__ C) {
  __shared__ __align__(16) unsigned short lds[24576];  // 48 KiB

  const int tid = threadIdx.x;
  const int wave = tid >> 6;
  const int lane = tid & 63;
  const int l15 = lane & 15, l4 = lane >> 4;
  const int wr = wave >> 2, wc = wave & 3;   // 2M x 4N wave grid; per-wave 64x64
  const int wv512 = wave * 512;

  // XCD-aware swizzle: 1024 blocks, 1024 % 8 == 0 -> bijective
  const int bid = (int)blockIdx.x;
  const int swz = (bid & 7) * 128 + (bid >> 3);
  const int bx = swz & 15;                   // 16 N-tiles (256 each)
  const int by = swz >> 4;                   // 64 M-tiles (128 each)
  const size_t bm = (size_t)by * 128;
  const size_t bn = (size_t)bx * 256;

  // stage source (pre-swizzled per thread): row = tid>>2 (A: 128 rows; B: +128 for j=1)
  // col8_src = (tid&3) ^ ((row>>1)&3) = (tid&3) ^ ((tid>>3)&3)
  const int srow = tid >> 2;
  const int scol = (tid & 3) ^ ((tid >> 3) & 3);
  const unsigned short* aP = A  + (bm + (size_t)srow) * K_DIM + scol * 8;
  const unsigned short* bP = Bt + (bn + (size_t)srow) * K_DIM + scol * 8;

  // ds_read bases (elem units); xk = (l4 ^ ((row>>1)&3))*8, (row>>1)&3 == (l15>>1)&3
  const int xk = (l4 ^ ((l15 >> 1) & 3)) * 8;
  const int aBase = (wr * 64 + l15) * 32 + xk;    // + mi*512 (16-row steps)
  const int bBase = (wc * 64 + l15) * 32 + xk;    // + ni*512

  f32x4 acc[4][4] = {};

  // ---- prologue: stage tile 0 -> slots 0; drain; barrier ----
  STG(0, 0);
  asm volatile("s_waitcnt vmcnt(0)" ::: "memory");
  __builtin_amdgcn_s_barrier();

  // ---- main loop: 128 K-tiles (BK=32) ----
  for (int t = 0; t < 126; t += 2) {
    KTILE(t,     0, 1, 0);
    KTILE(t + 1, 1, 1, 0);
  }
  KTILE(126, 0, 1, 0);   // stages tile 127 -> slot 1
  KTILE(127, 1, 0, 1);   // last tile: no stage, no barrier

  // ---- epilogue: fused BN + GELU + ReLU ----
  const int row0 = (int)bm + wr * 64;
  const int col0 = (int)bn + wc * 64;
#pragma unroll
  for (int ni = 0; ni < 4; ++ni) {
    const int col = col0 + ni * 16 + l15;
    const float inv = rsqrtf(var[col] + EPS) * gam[col];
    const float shift = fmaf(-mu[col], inv, bet[col]);
#pragma unroll
    for (int mi = 0; mi < 4; ++mi) {
      const int r0 = row0 + mi * 16 + l4 * 4;
#pragma unroll
      for (int r = 0; r < 4; ++r)
        C[(size_t)(r0 + r) * N_DIM + col] = fused_epilogue(acc[mi][ni][r], inv, shift);
    }
  }
}

// ---------- fallback (only if ws too small): fp32 tiled GEMM ----------

__global__ __launch_bounds__(256) void gemm_f32_fallback(
    const float* __restrict__ A, const float* __restrict__ W,
    const float* __restrict__ gam, const float* __restrict__ bet,
    const float* __restrict__ mu, const float* __restrict__ var,
    float* __restrict__ C) {
  __shared__ float As[16][65];
  __shared__ float Bs[16][65];
  const int tid = threadIdx.x;
  const int tx = tid & 15, ty = tid >> 4;
  const int bn0 = blockIdx.x * 64, bm0 = blockIdx.y * 64;
  float acc[4][4] = {};
  for (int k0 = 0; k0 < K_DIM; k0 += 16) {
#pragma unroll
    for (int j = 0; j < 4; ++j)
      As[tid & 15][(tid >> 4) * 4 + j] =
          A[(size_t)(bm0 + (tid >> 4) * 4 + j) * K_DIM + k0 + (tid & 15)];
#pragma unroll
    for (int j = 0; j < 4; ++j)
      Bs[tid >> 4][(tid & 15) * 4 + j] =
          W[(size_t)(k0 + (tid >> 4)) * N_DIM + bn0 + (tid & 15) * 4 + j];
    __syncthreads();
#pragma unroll
    for (int kk = 0; kk < 16; ++kk) {
      float a_[4], b_[4];
#pragma unroll
      for (int i = 0; i < 4; ++i) a_[i] = As[kk][ty * 4 + i];
#pragma unroll
      for (int j = 0; j < 4; ++j) b_[j] = Bs[kk][tx * 4 + j];
#pragma unroll
      for (int i = 0; i < 4; ++i)
#pragma unroll
        for (int j = 0; j < 4; ++j)
          acc[i][j] = fmaf(a_[i], b_[j], acc[i][j]);
    }
    __syncthreads();
  }
#pragma unroll
  for (int j = 0; j < 4; ++j) {
    const int col = bn0 + tx * 4 + j;
    const float inv = rsqrtf(var[col] + EPS) * gam[col];
    const float shift = fmaf(-mu[col], inv, bet[col]);
#pragma unroll
    for (int i = 0; i < 4; ++i) {
      float y = fmaf(acc[i][j], inv, shift);
      float y2 = y * y;
      float z = fmaf(0.044715f * y2, y, y);
      float e = __builtin_amdgcn_exp2f(-2.3022081f * z);
      float ge = y * __builtin_amdgcn_rcpf(1.0f + e);
      C[(size_t)(bm0 + ty * 4 + i) * N_DIM + col] = fmaxf(ge, 0.0f);
    }
  }
}

// ---------- launch ----------

extern "C" void kernel_launch(void* const* d_in, const int* in_sizes, int n_in,
                              void* d_out, int out_size, void* d_ws, size_t ws_size,
                              hipStream_t stream) {
  const float* x  = (const float*)d_in[0];
  const float* w  = (const float*)d_in[1];
  const float* gg = (const float*)d_in[2];
  const float* bb = (const float*)d_in[3];
  const float* mu = (const float*)d_in[4];
  const float* vr = (const float*)d_in[5];
  float* out = (float*)d_out;

  const size_t xb_bytes = (size_t)M_DIM * K_DIM * 2;
  const size_t wt_bytes = (size_t)K_DIM * N_DIM * 2;

  if (ws_size >= xb_bytes + wt_bytes) {
    unsigned short* xb = (unsigned short*)d_ws;
    unsigned short* wt = xb + (size_t)M_DIM * K_DIM;
    cvt_x_kernel<<<dim3((M_DIM * (size_t)K_DIM) / 8 / 256), dim3(256), 0, stream>>>(x, xb);
    cvt_w_transpose<<<dim3(N_DIM / 32, K_DIM / 32), dim3(256), 0, stream>>>(w, wt);
    gemm_bf16_fused<<<dim3((M_DIM / 128) * (N_DIM / 256)), dim3(512), 0, stream>>>(
        xb, wt, gg, bb, mu, vr, out);
  } else {
    gemm_f32_fallback<<<dim3(N_DIM / 64, M_DIM / 64), dim3(256), 0, stream>>>(
        x, w, gg, bb, mu, vr, out);
  }
}

// Round 15
// 290.314 us; speedup vs baseline: 2.2343x; 1.1346x over previous
//
#include <hip/hip_runtime.h>
#include <hip/hip_bf16.h>
#include <cstdint>
#include <cstddef>

#define M_DIM 8192
#define K_DIM 4096
#define N_DIM 4096
#define EPS 1e-5f

typedef __bf16 bf16x8 __attribute__((ext_vector_type(8)));
typedef unsigned short u16x8 __attribute__((ext_vector_type(8)));
typedef float f32x4 __attribute__((ext_vector_type(4)));

// ---------- helpers ----------

__device__ __forceinline__ unsigned short f2bf(float f) {
  unsigned int u = __builtin_bit_cast(unsigned int, f);
  u += 0x7fffu + ((u >> 16) & 1u);   // round-to-nearest-even
  return (unsigned short)(u >> 16);
}

// GELU(tanh-approx)+ReLU via identity 0.5y(1+tanh(w)) = y*sigmoid(2w):
// ge = y / (1 + exp2(-c2*z)), z = y + 0.044715 y^3, c2 = 2*0.7978845608*log2(e)
__device__ __forceinline__ float fused_epilogue(float acc, float inv, float shift) {
  float y = fmaf(acc, inv, shift);
  float y2 = y * y;
  float z = fmaf(0.044715f * y2, y, y);
  float e = __builtin_amdgcn_exp2f(-2.3022081f * z);
  float ge = y * __builtin_amdgcn_rcpf(1.0f + e);
  return fmaxf(ge, 0.0f);
}

__device__ __forceinline__ void gload_lds16(const void* gsrc, void* ldst) {
  __builtin_amdgcn_global_load_lds(
      (const __attribute__((address_space(1))) void*)gsrc,
      (__attribute__((address_space(3))) void*)ldst,
      16, 0, 0);
}

// ---------- pre-pass: fp32 -> bf16 conversions ----------

__global__ __launch_bounds__(256) void cvt_x_kernel(const float* __restrict__ x,
                                                    unsigned short* __restrict__ xb) {
  size_t i = ((size_t)blockIdx.x * 256 + threadIdx.x) * 8;
  float4 a = *reinterpret_cast<const float4*>(x + i);
  float4 b = *reinterpret_cast<const float4*>(x + i + 4);
  u16x8 o;
  o[0] = f2bf(a.x); o[1] = f2bf(a.y); o[2] = f2bf(a.z); o[3] = f2bf(a.w);
  o[4] = f2bf(b.x); o[5] = f2bf(b.y); o[6] = f2bf(b.z); o[7] = f2bf(b.w);
  *reinterpret_cast<u16x8*>(xb + i) = o;
}

// W [K][N] fp32 -> Wt [N][K] bf16 (transpose + convert)
__global__ __launch_bounds__(256) void cvt_w_transpose(const float* __restrict__ W,
                                                       unsigned short* __restrict__ Wt) {
  __shared__ float tile[32][33];
  const int tx = threadIdx.x & 31;
  const int tg = threadIdx.x >> 5;
  const int n0 = blockIdx.x * 32;
  const int k0 = blockIdx.y * 32;
#pragma unroll
  for (int j = 0; j < 4; ++j) {
    int k = tg * 4 + j;
    tile[k][tx] = W[(size_t)(k0 + k) * N_DIM + n0 + tx];
  }
  __syncthreads();
#pragma unroll
  for (int j = 0; j < 4; ++j) {
    int n = tg * 4 + j;
    Wt[(size_t)(n0 + n) * K_DIM + k0 + tx] = f2bf(tile[tx][n]);
  }
}

// ---------- main GEMM: 256x256, BK=64, 8 waves, 8-phase (m201 template) ----------
// Best-measured structure (R10 ~ R4, 247-251us GEMM, 1100 TF). Full T-stack:
// T1 bijective XCD swizzle, T2 0-conflict XOR swizzle, T3 phase interleave,
// T4 counted vmcnt(4) (never 0 in-loop), T5 setprio around MFMA clusters.
// 4 phases per K-tile. ph0 reads ALL B frags (held in regs whole tile -> B-stage
// in ph2/3 hazard-free) + A mi{0,1}; ph1/2/3 read A quarters; one half-tile
// stage per phase; vmcnt(4) once per tile at ph3 (retires A(t+1)+B(t+1),
// leaves B(t+2) x4 in flight across the barrier).

#define STG_A(h, j, PAR, T)                                                        \
  gload_lds16(aS + (size_t)((h)*128 + 64*(j)) * K_DIM + (size_t)((T) + 1) * 64,    \
              &lds[(2*(1-(PAR)) + (h)) * 8192 + (wave + 8*(j)) * 512])

#define STG_B(h, j, PAR, T)                                                        \
  gload_lds16(bS + (size_t)((h)*128 + 64*(j)) * K_DIM + (size_t)((T) + 2) * 64,    \
              &lds[32768 + (2*(PAR) + (h)) * 8192 + (wave + 8*(j)) * 512])

#define LDS_FRAG(off) __builtin_bit_cast(bf16x8, *(const u16x8*)&lds[(off)])

#define RD_A(q, mi)                                                                \
  afr[q][0] = LDS_FRAG(sa + aro + (mi) * 1024 + xk0);                              \
  afr[q][1] = LDS_FRAG(sa + aro + (mi) * 1024 + xk1)

#define MF16(p)                                                                    \
  __builtin_amdgcn_s_setprio(1);                                                   \
  _Pragma("unroll") for (int kh = 0; kh < 2; ++kh)                                 \
  _Pragma("unroll") for (int q = 0; q < 2; ++q)                                    \
  _Pragma("unroll") for (int ni = 0; ni < 4; ++ni)                                 \
    acc[2*(p) + q][ni] = __builtin_amdgcn_mfma_f32_16x16x32_bf16(                  \
        afr[q][kh], bfr[ni][kh], acc[2*(p) + q][ni], 0, 0, 0);                     \
  __builtin_amdgcn_s_setprio(0)

#define BAR_IN                                                                     \
  asm volatile("" ::: "memory");                                                   \
  __builtin_amdgcn_s_barrier();                                                    \
  asm volatile("s_waitcnt lgkmcnt(0)" ::: "memory")

#define BAR_OUT                                                                    \
  asm volatile("" ::: "memory");                                                   \
  __builtin_amdgcn_s_barrier()

#define KTILE(T, PAR, STA, STB, VM) do {                                           \
  const int sa = (PAR) * 16384 + saW;                                              \
  const int sb = (PAR) * 16384 + sbW;                                              \
  bf16x8 bfr[4][2], afr[2][2];                                                     \
  /* ---- phase 0: all B + A mi{0,1}; stage A(T+1) half0 ---- */                   \
  _Pragma("unroll") for (int ni = 0; ni < 4; ++ni) {                               \
    bfr[ni][0] = LDS_FRAG(sb + bro + ni * 1024 + xk0);                             \
    bfr[ni][1] = LDS_FRAG(sb + bro + ni * 1024 + xk1);                             \
  }                                                                                \
  RD_A(0, 0); RD_A(1, 1);                                                          \
  if (STA) { STG_A(0, 0, PAR, T); STG_A(0, 1, PAR, T); }                           \
  BAR_IN;                                                                          \
  MF16(0);                                                                         \
  BAR_OUT;                                                                         \
  /* ---- phase 1: A mi{2,3}; stage A(T+1) half1 ---- */                           \
  RD_A(0, 2); RD_A(1, 3);                                                          \
  if (STA) { STG_A(1, 0, PAR, T); STG_A(1, 1, PAR, T); }                           \
  BAR_IN;                                                                          \
  MF16(1);                                                                         \
  BAR_OUT;                                                                         \
  /* ---- phase 2: A mi{4,5}; stage B(T+2) half0 ---- */                           \
  RD_A(0, 4); RD_A(1, 5);                                                          \
  if (STB) { STG_B(0, 0, PAR, T); STG_B(0, 1, PAR, T); }                           \
  BAR_IN;                                                                          \
  MF16(2);                                                                         \
  BAR_OUT;                                                                         \
  /* ---- phase 3: A mi{6,7}; stage B(T+2) half1; vmcnt at tile end ---- */        \
  RD_A(0, 6); RD_A(1, 7);                                                          \
  if (STB) { STG_B(1, 0, PAR, T); STG_B(1, 1, PAR, T); }                           \
  BAR_IN;                                                                          \
  MF16(3);                                                                         \
  if ((VM) >= 0) {                                                                 \
    if ((VM) == 4)      asm volatile("s_waitcnt vmcnt(4)" ::: "memory");           \
    else                asm volatile("s_waitcnt vmcnt(0)" ::: "memory");           \
    BAR_OUT;                                                                       \
  }                                                                                \
} while (0)

__global__ __launch_bounds__(512, 2) void gemm_bf16_fused(
    const unsigned short* __restrict__ A,
    const unsigned short* __restrict__ Bt,
    const float* __restrict__ gam, const float* __restrict__ bet,
    const float* __restrict__ mu, const float* __restrict__ var,
    float* __restrict__ C) {
  __shared__ __align__(16) unsigned short lds[65536];  // 128 KiB

  const int tid = threadIdx.x;
  const int wave = tid >> 6;
  const int lane = tid & 63;
  const int l15 = lane & 15, l4 = lane >> 4;
  const int wr = wave >> 2, wc = wave & 3;   // 2x4 wave grid; per-wave out 128x64

  // XCD-aware swizzle: 512 blocks, 512 % 8 == 0 -> bijective
  const int bid = (int)blockIdx.x;
  const int swz = (bid & 7) * 64 + (bid >> 3);
  const int bx = swz & 15;                   // 16 N-tiles
  const int by = swz >> 4;                   // 32 M-tiles
  const size_t bm = (size_t)by * 256;
  const size_t bn = (size_t)bx * 256;

  // stage source addresses (pre-swizzled global per lane; LDS dest linear)
  const int lr = lane >> 3, lc = lane & 7;
  const unsigned short* aS = A + (bm + (size_t)(wave * 8 + lr)) * K_DIM + (lc ^ lr) * 8;
  const unsigned short* bS = Bt + (bn + (size_t)(wave * 8 + lr)) * K_DIM + (lc ^ lr) * 8;

  // ds_read fragment offsets (u16 units); col8' = col8 ^ (row&7), row&7 == l15&7
  const int xk0 = ((l4)     ^ (l15 & 7)) * 8;
  const int xk1 = ((l4 | 4) ^ (l15 & 7)) * 8;
  const int aro = l15 * 64;
  const int bro = (wc & 1) * 4096 + l15 * 64;
  const int saW = wr * 8192;
  const int sbW = 32768 + (wc >> 1) * 8192;

  f32x4 acc[8][4] = {};

  // ---- prologue: stage A(0), B(0), B(1); wait A(0)+B(0) landed ----
  STG_A(0, 0, 1, -1); STG_A(0, 1, 1, -1);
  STG_A(1, 0, 1, -1); STG_A(1, 1, 1, -1);
  asm volatile("" ::: "memory");
  STG_B(0, 0, 0, -2); STG_B(0, 1, 0, -2);
  STG_B(1, 0, 0, -2); STG_B(1, 1, 0, -2);
  asm volatile("" ::: "memory");
  STG_B(0, 0, 1, -1); STG_B(0, 1, 1, -1);
  STG_B(1, 0, 1, -1); STG_B(1, 1, 1, -1);
  asm volatile("s_waitcnt vmcnt(4)" ::: "memory");
  __builtin_amdgcn_s_barrier();

  // ---- main loop: 64 K-tiles ----
  for (int t = 0; t < 60; t += 2) {
    KTILE(t,     0, 1, 1, 4);
    KTILE(t + 1, 1, 1, 1, 4);
  }
  KTILE(60, 0, 1, 1, 4);
  KTILE(61, 1, 1, 1, 4);   // stages A(62), B(63)
  KTILE(62, 0, 1, 0, 0);   // stages A(63); drain all outstanding
  KTILE(63, 1, 0, 0, -1);  // no stages, nothing outstanding, no final barrier

  // ---- epilogue: fused BN + GELU + ReLU ----
  const int row0 = (int)bm + wr * 128;
  const int col0 = (int)bn + wc * 64;
#pragma unroll
  for (int ni = 0; ni < 4; ++ni) {
    const int col = col0 + ni * 16 + l15;
    const float inv = rsqrtf(var[col] + EPS) * gam[col];
    const float shift = fmaf(-mu[col], inv, bet[col]);
#pragma unroll
    for (int mi = 0; mi < 8; ++mi) {
      const int r0 = row0 + mi * 16 + l4 * 4;
#pragma unroll
      for (int r = 0; r < 4; ++r)
        C[(size_t)(r0 + r) * N_DIM + col] = fused_epilogue(acc[mi][ni][r], inv, shift);
    }
  }
}

// ---------- fallback (only if ws too small): fp32 tiled GEMM ----------

__global__ __launch_bounds__(256) void gemm_f32_fallback(
    const float* __restrict__ A, const float* __restrict__ W,
    const float* __restrict__ gam, const float* __restrict__ bet,
    const float* __restrict__ mu, const float* __restrict__ var,
    float* __restrict__ C) {
  __shared__ float As[16][65];
  __shared__ float Bs[16][65];
  const int tid = threadIdx.x;
  const int tx = tid & 15, ty = tid >> 4;
  const int bn0 = blockIdx.x * 64, bm0 = blockIdx.y * 64;
  float acc[4][4] = {};
  for (int k0 = 0; k0 < K_DIM; k0 += 16) {
#pragma unroll
    for (int j = 0; j < 4; ++j)
      As[tid & 15][(tid >> 4) * 4 + j] =
          A[(size_t)(bm0 + (tid >> 4) * 4 + j) * K_DIM + k0 + (tid & 15)];
#pragma unroll
    for (int j = 0; j < 4; ++j)
      Bs[tid >> 4][(tid & 15) * 4 + j] =
          W[(size_t)(k0 + (tid >> 4)) * N_DIM + bn0 + (tid & 15) * 4 + j];
    __syncthreads();
#pragma unroll
    for (int kk = 0; kk < 16; ++kk) {
      float a_[4], b_[4];
#pragma unroll
      for (int i = 0; i < 4; ++i) a_[i] = As[kk][ty * 4 + i];
#pragma unroll
      for (int j = 0; j < 4; ++j) b_[j] = Bs[kk][tx * 4 + j];
#pragma unroll
      for (int i = 0; i < 4; ++i)
#pragma unroll
        for (int j = 0; j < 4; ++j)
          acc[i][j] = fmaf(a_[i], b_[j], acc[i][j]);
    }
    __syncthreads();
  }
#pragma unroll
  for (int j = 0; j < 4; ++j) {
    const int col = bn0 + tx * 4 + j;
    const float inv = rsqrtf(var[col] + EPS) * gam[col];
    const float shift = fmaf(-mu[col], inv, bet[col]);
#pragma unroll
    for (int i = 0; i < 4; ++i) {
      float y = fmaf(acc[i][j], inv, shift);
      float y2 = y * y;
      float z = fmaf(0.044715f * y2, y, y);
      float e = __builtin_amdgcn_exp2f(-2.3022081f * z);
      float ge = y * __builtin_amdgcn_rcpf(1.0f + e);
      C[(size_t)(bm0 + ty * 4 + i) * N_DIM + col] = fmaxf(ge, 0.0f);
    }
  }
}

// ---------- launch ----------

extern "C" void kernel_launch(void* const* d_in, const int* in_sizes, int n_in,
                              void* d_out, int out_size, void* d_ws, size_t ws_size,
                              hipStream_t stream) {
  const float* x  = (const float*)d_in[0];
  const float* w  = (const float*)d_in[1];
  const float* gg = (const float*)d_in[2];
  const float* bb = (const float*)d_in[3];
  const float* mu = (const float*)d_in[4];
  const float* vr = (const float*)d_in[5];
  float* out = (float*)d_out;

  const size_t xb_bytes = (size_t)M_DIM * K_DIM * 2;
  const size_t wt_bytes = (size_t)K_DIM * N_DIM * 2;

  if (ws_size >= xb_bytes + wt_bytes) {
    unsigned short* xb = (unsigned short*)d_ws;
    unsigned short* wt = xb + (size_t)M_DIM * K_DIM;
    cvt_x_kernel<<<dim3((M_DIM * (size_t)K_DIM) / 8 / 256), dim3(256), 0, stream>>>(x, xb);
    cvt_w_transpose<<<dim3(N_DIM / 32, K_DIM / 32), dim3(256), 0, stream>>>(w, wt);
    gemm_bf16_fused<<<dim3((M_DIM / 256) * (N_DIM / 256)), dim3(512), 0, stream>>>(
        xb, wt, gg, bb, mu, vr, out);
  } else {
    gemm_f32_fallback<<<dim3(N_DIM / 64, M_DIM / 64), dim3(256), 0, stream>>>(
        x, w, gg, bb, mu, vr, out);
  }
}